// Round 17
// baseline (250.425 us; speedup 1.0000x reference)
//
#include <hip/hip_runtime.h>

#define CH 128          // C_IN == C_OUT == 128
#define SUMS_BLOCK 512
#define CHUNK_E 4096    // records per chunk = private recsTmp window
#define RPT 16          // records per thread in passA (CHUNK_E / 256)
#define BUCKET_BITS 10  // 1024 keys per bucket
#define BKEYS (1 << BUCKET_BITS)
#define NBMAX 512       // max buckets (LDS arrays padded to this)
#define STAG_CAP 18432  // passB LDS out-buffer capacity

__device__ inline ushort f2bf(float f) {          // RNE f32 -> bf16
    unsigned b = __float_as_uint(f);
    return (ushort)((b + 0x7FFF + ((b >> 16) & 1)) >> 16);
}

// ---------- W -> bf16 conversion ----------
__global__ void conv_w_kernel(const float* __restrict__ W,
                              ushort* __restrict__ Wb) {
    int i = blockIdx.x * blockDim.x + threadIdx.x;
    if (i < CH * CH) Wb[i] = f2bf(W[i]);
}

// ---------- pass A v4: single-read sort emitting final 4B rec + 2B key ----
// Triple key space: Phi_inv i -> idxA[i]; Phi -> n+idxB[e]; F -> 2n+idxC[e].
// Emits recs4Tmp[pos] = (c<<15)|bf15(v)  (FINAL record format, values all
// positive so bf16 sign bit is 0) and keyTmp[pos] = key&1023.
__global__ __launch_bounds__(256) void passA_sort(const int* __restrict__ idxA,
                                                  const float* __restrict__ valA,
                                                  const int* __restrict__ idxB,
                                                  const float* __restrict__ valB,
                                                  const int* __restrict__ idxC,
                                                  const float* __restrict__ valC,
                                                  const float* __restrict__ theta,
                                                  int nnz, int n, int nb,
                                                  int* __restrict__ locA,
                                                  unsigned* __restrict__ recs4Tmp,
                                                  ushort* __restrict__ keyTmp) {
    __shared__ int hist[NBMAX];
    __shared__ int sc[NBMAX];
    __shared__ int cur[NBMAX];
    int t = threadIdx.x;
    hist[t] = 0; hist[t + 256] = 0;
    __syncthreads();

    int base = blockIdx.x * CHUNK_E;
    int end = min(base + CHUNK_E, 3 * nnz);
    int csize = end - base;
    int rbeg = base + t * RPT;

    unsigned px[RPT];   // final packed record
    ushort pk[RPT];     // key low bits
    short pb[RPT];      // bucket id

    int nvalid = 0;
    if (rbeg + RPT <= nnz) {
        #pragma unroll
        for (int r4 = 0; r4 < RPT / 4; ++r4) {
            int4 k4 = *reinterpret_cast<const int4*>(&idxA[rbeg + r4 * 4]);
            int4 c4 = *reinterpret_cast<const int4*>(&idxA[nnz + rbeg + r4 * 4]);
            float4 v4 = *reinterpret_cast<const float4*>(&valA[rbeg + r4 * 4]);
            int kk[4] = {k4.x, k4.y, k4.z, k4.w};
            int cc[4] = {c4.x, c4.y, c4.z, c4.w};
            float vv[4] = {v4.x, v4.y, v4.z, v4.w};
            #pragma unroll
            for (int u = 0; u < 4; ++u) {
                int r = r4 * 4 + u;
                px[r] = ((unsigned)cc[u] << 15) | ((unsigned)f2bf(vv[u]) & 0x7FFFu);
                pk[r] = (ushort)(kk[u] & (BKEYS - 1));
                pb[r] = (short)(kk[u] >> BUCKET_BITS);
                atomicAdd(&hist[pb[r]], 1);
            }
        }
        nvalid = RPT;
    } else if (rbeg >= nnz && rbeg + RPT <= 2 * nnz) {
        int e0 = rbeg - nnz;
        #pragma unroll
        for (int r4 = 0; r4 < RPT / 4; ++r4) {
            int4 k4 = *reinterpret_cast<const int4*>(&idxB[e0 + r4 * 4]);
            int4 c4 = *reinterpret_cast<const int4*>(&idxB[nnz + e0 + r4 * 4]);
            float4 v4 = *reinterpret_cast<const float4*>(&valB[e0 + r4 * 4]);
            int kk[4] = {k4.x, k4.y, k4.z, k4.w};
            int cc[4] = {c4.x, c4.y, c4.z, c4.w};
            float vv[4] = {v4.x, v4.y, v4.z, v4.w};
            #pragma unroll
            for (int u = 0; u < 4; ++u) {
                int r = r4 * 4 + u;
                int key = n + kk[u];
                px[r] = ((unsigned)cc[u] << 15) |
                        ((unsigned)f2bf(vv[u] * theta[cc[u]]) & 0x7FFFu);
                pk[r] = (ushort)(key & (BKEYS - 1));
                pb[r] = (short)(key >> BUCKET_BITS);
                atomicAdd(&hist[pb[r]], 1);
            }
        }
        nvalid = RPT;
    } else if (rbeg >= 2 * nnz && rbeg + RPT <= 3 * nnz) {
        int e0 = rbeg - 2 * nnz;
        #pragma unroll
        for (int r4 = 0; r4 < RPT / 4; ++r4) {
            int4 k4 = *reinterpret_cast<const int4*>(&idxC[e0 + r4 * 4]);
            int4 c4 = *reinterpret_cast<const int4*>(&idxC[nnz + e0 + r4 * 4]);
            float4 v4 = *reinterpret_cast<const float4*>(&valC[e0 + r4 * 4]);
            int kk[4] = {k4.x, k4.y, k4.z, k4.w};
            int cc[4] = {c4.x, c4.y, c4.z, c4.w};
            float vv[4] = {v4.x, v4.y, v4.z, v4.w};
            #pragma unroll
            for (int u = 0; u < 4; ++u) {
                int r = r4 * 4 + u;
                int key = 2 * n + kk[u];
                px[r] = ((unsigned)cc[u] << 15) | ((unsigned)f2bf(vv[u]) & 0x7FFFu);
                pk[r] = (ushort)(key & (BKEYS - 1));
                pb[r] = (short)(key >> BUCKET_BITS);
                atomicAdd(&hist[pb[r]], 1);
            }
        }
        nvalid = RPT;
    } else {
        #pragma unroll
        for (int r = 0; r < RPT; ++r) {
            int i = rbeg + r;
            if (i >= end) break;
            int key, c;
            float v;
            if (i < nnz) {
                key = idxA[i];
                c = idxA[nnz + i];
                v = valA[i];
            } else if (i < 2 * nnz) {
                int e = i - nnz;
                key = n + idxB[e];
                c = idxB[nnz + e];
                v = valB[e] * theta[c];
            } else {
                int e = i - 2 * nnz;
                key = 2 * n + idxC[e];
                c = idxC[nnz + e];
                v = valC[e];
            }
            px[r] = ((unsigned)c << 15) | ((unsigned)f2bf(v) & 0x7FFFu);
            pk[r] = (ushort)(key & (BKEYS - 1));
            pb[r] = (short)(key >> BUCKET_BITS);
            atomicAdd(&hist[pb[r]], 1);
            ++nvalid;
        }
    }
    __syncthreads();

    sc[t] = hist[t]; sc[t + 256] = hist[t + 256];
    __syncthreads();
    for (int off = 1; off < NBMAX; off <<= 1) {
        int a = (t >= off) ? sc[t - off] : 0;
        int b2 = (t + 256 >= off) ? sc[t + 256 - off] : 0;
        __syncthreads();
        sc[t] += a; sc[t + 256] += b2;
        __syncthreads();
    }
    cur[t] = sc[t] - hist[t];
    cur[t + 256] = sc[t + 256] - hist[t + 256];
    __syncthreads();

    for (int b = t; b <= nb; b += 256)
        locA[(size_t)blockIdx.x * (nb + 1) + b] = (b < nb) ? (sc[b] - hist[b]) : csize;

    #pragma unroll
    for (int r = 0; r < RPT; ++r) {
        if (r < nvalid) {
            int pos = atomicAdd(&cur[pb[r]], 1);
            recs4Tmp[(size_t)base + pos] = px[r];
            keyTmp[(size_t)base + pos] = pk[r];
        }
    }
}

// ---------- bucket totals ----------
__global__ __launch_bounds__(256) void bucket_totals(const int* __restrict__ locA,
                                                     int nchA, int nb,
                                                     int* __restrict__ tot) {
    __shared__ int red[256];
    int b = blockIdx.x;
    int t = threadIdx.x;
    int s = 0;
    for (int ch = t; ch < nchA; ch += 256) {
        const int* lc = &locA[(size_t)ch * (nb + 1)];
        s += lc[b + 1] - lc[b];
    }
    red[t] = s;
    __syncthreads();
    for (int off = 128; off > 0; off >>= 1) {
        if (t < off) red[t] += red[t + off];
        __syncthreads();
    }
    if (t == 0) tot[b] = red[0];
}

__global__ void scan_sums_kernel(int* __restrict__ chunk_sums, int nchunks) {
    __shared__ int tmp[SUMS_BLOCK];
    __shared__ int carry_s;
    int tid = threadIdx.x;
    if (tid == 0) carry_s = 0;
    __syncthreads();
    for (int base = 0; base < nchunks; base += SUMS_BLOCK) {
        int i = base + tid;
        int v = (i < nchunks) ? chunk_sums[i] : 0;
        tmp[tid] = v;
        __syncthreads();
        for (int off = 1; off < SUMS_BLOCK; off <<= 1) {
            int y = (tid >= off) ? tmp[tid - off] : 0;
            __syncthreads();
            tmp[tid] += y;
            __syncthreads();
        }
        int c = carry_s;
        if (i < nchunks) chunk_sums[i] = tmp[tid] - v + c;   // exclusive
        int total = tmp[SUMS_BLOCK - 1];
        __syncthreads();
        if (tid == 0) carry_s = c + total;
        __syncthreads();
    }
}

// ---------- pass B v3: compact key hist, 4B payload, LDS out-buffer -------
__global__ __launch_bounds__(1024) void passB_kernel(const unsigned* __restrict__ recs4Tmp,
                                                     const ushort* __restrict__ keyTmp,
                                                     const int* __restrict__ locA,
                                                     const int* __restrict__ bsArr,
                                                     int nchA, int nb, int n3,
                                                     int* __restrict__ start_g,
                                                     int* __restrict__ counts_g,
                                                     unsigned* __restrict__ recs) {
    __shared__ int hist[BKEYS];          // 4 KB
    __shared__ int scan[BKEYS];          // 4 KB
    __shared__ unsigned outb[STAG_CAP];  // 72 KB
    int b = blockIdx.x;
    int t = threadIdx.x;
    int wave = t >> 6, lane = t & 63;
    int grp = lane >> 4, gl = lane & 15;
    int bs = bsArr[b];
    hist[t] = 0;
    __syncthreads();

    // phase 1: key histogram from the COMPACT key array (2 B/record)
    for (int ch = wave * 4 + grp; ch < nchA; ch += 64) {
        const int* lc = &locA[(size_t)ch * (nb + 1)];
        int ls = lc[b], le = lc[b + 1];
        size_t cb = (size_t)ch * CHUNK_E;
        for (int k = ls + gl; k < le; k += 16)
            atomicAdd(&hist[keyTmp[cb + k]], 1);
    }
    __syncthreads();

    int v = hist[t];
    scan[t] = v;
    __syncthreads();
    for (int off = 1; off < BKEYS; off <<= 1) {
        int y = (t >= off) ? scan[t - off] : 0;
        __syncthreads();
        scan[t] += y;
        __syncthreads();
    }
    int excl = scan[t] - v;
    int key = (b << BUCKET_BITS) + t;
    if (key < n3) {
        start_g[key] = bs + excl;
        counts_g[key] = v;
    }
    int totalB = scan[BKEYS - 1];
    hist[t] = excl;                      // reuse as cursor
    __syncthreads();

    if (totalB <= STAG_CAP) {
        // phase 3: scatter final 4B records into LDS out-buffer
        for (int ch = wave * 4 + grp; ch < nchA; ch += 64) {
            const int* lc = &locA[(size_t)ch * (nb + 1)];
            int ls = lc[b], le = lc[b + 1];
            size_t cb = (size_t)ch * CHUNK_E;
            for (int k = ls + gl; k < le; k += 16) {
                int kk = keyTmp[cb + k];
                int pos = atomicAdd(&hist[kk], 1);
                outb[pos] = recs4Tmp[cb + k];
            }
        }
        __syncthreads();
        // phase 4: linear coalesced flush
        for (int k = t; k < totalB; k += 1024)
            recs[(size_t)bs + k] = outb[k];
    } else {
        // fallback (statistically unreachable): direct global scatter
        for (int ch = wave * 4 + grp; ch < nchA; ch += 64) {
            const int* lc = &locA[(size_t)ch * (nb + 1)];
            int ls = lc[b], le = lc[b + 1];
            size_t cb = (size_t)ch * CHUNK_E;
            for (int k = ls + gl; k < le; k += 16) {
                int kk = keyTmp[cb + k];
                int pos = atomicAdd(&hist[kk], 1);
                recs[(size_t)bs + pos] = recs4Tmp[cb + k];
            }
        }
    }
}

// ---------- Pull SpMM v3: 16 lanes/row, uint4 gathers, shfl broadcast -----
// Each 16-lane group owns one row (4 rows/wave, 16 rows/block). 16 records
// are loaded by one cooperative load, broadcast via __shfl(w=16). Each lane
// gathers 16 B (8 bf16 channels) -> 256 B/row in one instruction per group.
__global__ __launch_bounds__(256) void pull_spmm_bf16(
        const unsigned* __restrict__ recs,
        const int* __restrict__ start,
        const int* __restrict__ counts,
        const ushort* __restrict__ dense,   // bf16 rows of 128
        ushort* __restrict__ outb,          // bf16 out (or null)
        float* __restrict__ outf,           // f32 out (or null)
        int n, int do_relu) {
    int grp = threadIdx.x >> 4;             // 16 row-groups per block
    int lane = threadIdx.x & 15;
    int row = blockIdx.x * 16 + grp;
    if (row >= n) return;
    int s = start[row];
    int cnt = counts[row];
    const uint4* dp = reinterpret_cast<const uint4*>(dense);  // 16 uint4/row
    float a0 = 0, a1 = 0, a2 = 0, a3 = 0, a4 = 0, a5 = 0, a6 = 0, a7 = 0;

    #define ACC(dv, vf) \
        a0 = fmaf(vf, __uint_as_float((dv).x << 16), a0);           \
        a1 = fmaf(vf, __uint_as_float((dv).x & 0xFFFF0000u), a1);   \
        a2 = fmaf(vf, __uint_as_float((dv).y << 16), a2);           \
        a3 = fmaf(vf, __uint_as_float((dv).y & 0xFFFF0000u), a3);   \
        a4 = fmaf(vf, __uint_as_float((dv).z << 16), a4);           \
        a5 = fmaf(vf, __uint_as_float((dv).z & 0xFFFF0000u), a5);   \
        a6 = fmaf(vf, __uint_as_float((dv).w << 16), a6);           \
        a7 = fmaf(vf, __uint_as_float((dv).w & 0xFFFF0000u), a7);

    for (int jb = 0; jb < cnt; jb += 16) {
        int nbatch = min(16, cnt - jb);
        unsigned myrec = (lane < nbatch) ? recs[s + jb + lane] : 0u;
        int j = 0;
        for (; j + 4 <= nbatch; j += 4) {
            unsigned r0 = __shfl(myrec, j + 0, 16);
            unsigned r1 = __shfl(myrec, j + 1, 16);
            unsigned r2 = __shfl(myrec, j + 2, 16);
            unsigned r3 = __shfl(myrec, j + 3, 16);
            uint4 d0 = dp[(size_t)(r0 >> 15) * 16 + lane];
            uint4 d1 = dp[(size_t)(r1 >> 15) * 16 + lane];
            uint4 d2 = dp[(size_t)(r2 >> 15) * 16 + lane];
            uint4 d3 = dp[(size_t)(r3 >> 15) * 16 + lane];
            float v0 = __uint_as_float((r0 & 0x7FFFu) << 16);
            float v1 = __uint_as_float((r1 & 0x7FFFu) << 16);
            float v2 = __uint_as_float((r2 & 0x7FFFu) << 16);
            float v3 = __uint_as_float((r3 & 0x7FFFu) << 16);
            ACC(d0, v0) ACC(d1, v1) ACC(d2, v2) ACC(d3, v3)
        }
        for (; j < nbatch; ++j) {
            unsigned r0 = __shfl(myrec, j, 16);
            uint4 d0 = dp[(size_t)(r0 >> 15) * 16 + lane];
            float v0 = __uint_as_float((r0 & 0x7FFFu) << 16);
            ACC(d0, v0)
        }
    }
    #undef ACC

    if (do_relu) {
        a0 = fmaxf(a0, 0.0f); a1 = fmaxf(a1, 0.0f);
        a2 = fmaxf(a2, 0.0f); a3 = fmaxf(a3, 0.0f);
        a4 = fmaxf(a4, 0.0f); a5 = fmaxf(a5, 0.0f);
        a6 = fmaxf(a6, 0.0f); a7 = fmaxf(a7, 0.0f);
    }
    if (outb) {
        uint4 o;
        o.x = (unsigned)f2bf(a0) | ((unsigned)f2bf(a1) << 16);
        o.y = (unsigned)f2bf(a2) | ((unsigned)f2bf(a3) << 16);
        o.z = (unsigned)f2bf(a4) | ((unsigned)f2bf(a5) << 16);
        o.w = (unsigned)f2bf(a6) | ((unsigned)f2bf(a7) << 16);
        reinterpret_cast<uint4*>(outb)[(size_t)row * 16 + lane] = o;
    } else {
        float4 o0 = {a0, a1, a2, a3};
        float4 o1 = {a4, a5, a6, a7};
        *reinterpret_cast<float4*>(&outf[(size_t)row * CH + lane * 8]) = o0;
        *reinterpret_cast<float4*>(&outf[(size_t)row * CH + lane * 8 + 4]) = o1;
    }
}

// ---------- host-side orchestration ----------

extern "C" void kernel_launch(void* const* d_in, const int* in_sizes, int n_in,
                              void* d_out, int out_size, void* d_ws, size_t ws_size,
                              hipStream_t stream) {
    const int*   phi_idx  = (const int*)d_in[0];
    const float* phi_val  = (const float*)d_in[1];
    const int*   phii_idx = (const int*)d_in[2];
    const float* phii_val = (const float*)d_in[3];
    const int*   f_idx    = (const int*)d_in[4];
    const float* f_val    = (const float*)d_in[5];
    const float* W        = (const float*)d_in[6];
    const float* theta    = (const float*)d_in[7];

    const int nnz = in_sizes[1];            // 1,600,000
    const int n   = in_sizes[7];            // 100,000
    const int n3  = 3 * n;                  // triple key space
    const int total = 3 * nnz;              // 4.8M records

    const int nb   = (n3 + BKEYS - 1) >> BUCKET_BITS;               // 293 (<=511)
    const int nchA = (total + CHUNK_E - 1) / CHUNK_E;               // 1172

    float* out = (float*)d_out;

    // workspace (~75 MB). The 51.2 MB "dense region" holds recs4Tmp (19.2 MB)
    // + keyTmp (9.6 MB) during the build; after passB reused as filtered_bf16
    // [0,25.6) and z_bf16 [25.6,51.2).
    char* ws = (char*)d_ws;
    char*  dense_region = ws;
    unsigned* recs4Tmp = (unsigned*)dense_region;                        // 19.2 MB
    ushort* keyTmp  = (ushort*)(dense_region + (size_t)total * sizeof(unsigned)); // 9.6 MB
    ushort* filt_b  = (ushort*)dense_region;                             // 25.6 MB
    ushort* z_b     = (ushort*)(dense_region + (size_t)n * CH * sizeof(ushort));
    ws += (size_t)n * CH * sizeof(float);                  // 51.2 MB region
    unsigned* recs  = (unsigned*)ws;        ws += (size_t)total * sizeof(unsigned);
    int* counts     = (int*)ws;             ws += (size_t)n3 * sizeof(int);
    int* start      = (int*)ws;             ws += (size_t)n3 * sizeof(int);
    int* locA       = (int*)ws;             ws += (size_t)nchA * (nb + 1) * sizeof(int);
    int* tot        = (int*)ws;             ws += 4096;
    ushort* w_b     = (ushort*)ws;          ws += CH * CH * sizeof(ushort);

    const int row_blocks = (n + 15) / 16;   // 16 rows per 256-thread block

    // --- W -> bf16 (independent; overlaps build) ---
    conv_w_kernel<<<(CH * CH + 255) / 256, 256, 0, stream>>>(W, w_b);

    // --- radix CSR build: all three sparse matrices in one key space ---
    passA_sort<<<nchA, 256, 0, stream>>>(phii_idx, phii_val, phi_idx, phi_val,
                                         f_idx, f_val, theta,
                                         nnz, n, nb, locA, recs4Tmp, keyTmp);
    bucket_totals<<<nb, 256, 0, stream>>>(locA, nchA, nb, tot);
    scan_sums_kernel<<<1, SUMS_BLOCK, 0, stream>>>(tot, nb);
    passB_kernel<<<nb, 1024, 0, stream>>>(recs4Tmp, keyTmp, locA, tot, nchA, nb, n3,
                                          start, counts, recs);

    // 1) filtered = F @ W       (keys [2n,3n); W bf16 L1-resident; bf16 out)
    pull_spmm_bf16<<<row_blocks, 256, 0, stream>>>(
        recs, start + 2 * n, counts + 2 * n, w_b, filt_b, nullptr, n, 0);

    // 2) z = Phi_inv @ filtered (keys [0,n); bf16 in/out)
    pull_spmm_bf16<<<row_blocks, 256, 0, stream>>>(
        recs, start, counts, filt_b, z_b, nullptr, n, 0);

    // 3) out = relu(Phi @ (theta .* z))  (keys [n,2n); theta pre-folded; f32 out)
    pull_spmm_bf16<<<row_blocks, 256, 0, stream>>>(
        recs, start + n, counts + n, z_b, nullptr, out, n, 1);
}